// Round 1
// 279.901 us; speedup vs baseline: 1.0009x; 1.0009x over previous
//
#include <hip/hip_runtime.h>

#define ALPHA_MIN 0.8187307530779818f  // exp(-1/5)
#define ALPHA_MAX 0.9607894391523232f  // exp(-1/25)

typedef _Float16 f16;
typedef _Float16 f16x4 __attribute__((ext_vector_type(4)));
typedef _Float16 f16x8 __attribute__((ext_vector_type(8)));
typedef float f32x16 __attribute__((ext_vector_type(16)));

// Fixed problem shape
#define BB_ 32
#define TT_ 2048
#define KK_ 256
#define HH_ 512
#define TC_ 64               // timesteps per chunk
#define NC_ 32               // chunks
#define KH_ 128              // k-half (two halves of K=256)

// Barrier WITHOUT vmcnt drain: waits LDS ops only, leaves global loads in
// flight across the barrier (AITER-style). imm 0xC07F = vmcnt(63) expcnt(7)
// lgkmcnt(0) on gfx9 encoding.
__device__ __forceinline__ void barrier_lds() {
    __builtin_amdgcn_s_waitcnt(0xC07F);
    __builtin_amdgcn_s_barrier();
}

// ============================ fused kernel v5 ===============================
// grid 256 = (nt<<5)|b -> XCD = b%8: the 8 n-panel blocks of batch b share
// X[b] (2 MB) in one XCD L2.
// block 448 = 7 waves, ROLE-SPECIALIZED producer/consumer:
//   waves 0-3 : MFMA only (one 32x32 mfma tile each; zero cvt VALU on their
//               critical path). 4 MFMA waves/CU = matrix-pipe saturating.
//   waves 4-5 : stagers — global float4 loads + fp32->f16 hi/lo split +
//               swizzled LDS write, double-buffered one k-half ahead.
//   wave  6   : LIF scan, consumes chunk c-1 from wxbuf.
// A-LDS is [2]-buffered: phase s computes buf[s&1] while stagers fill
// buf[(s+1)&1]; loads for half-step s+2 issued during phase s -> a full
// ~1k-cycle phase of latency cover. 2 barriers/chunk (was 4), 65 total.
// fp16-split: C = Ah*Bh + 2^-11*(Ah*Bl + Al*Bh); B-panel in registers.
__global__ __launch_bounds__(448, 1) void lif_fused5(
    const float* __restrict__ X,      // (B,T,K)
    const float* __restrict__ W,      // (H,K)
    const float* __restrict__ alpha,  // (H)
    const float* __restrict__ u0,     // (B,H)
    const float* __restrict__ s0,     // (B,H)
    float* __restrict__ out)          // (B,T,H)
{
    __shared__ f16 Ah[2][TC_ * KH_];         // 2 x 16 KB (swizzled 8-f16 groups)
    __shared__ f16 Al[2][TC_ * KH_];         // 2 x 16 KB
    __shared__ float wxbuf[2][TC_ * 64];     // 32 KB
    // total LDS = 96 KB

    const int b  = blockIdx.x & 31;
    const int nt = blockIdx.x >> 5;
    const int n0 = nt * 64;

    const int tid  = threadIdx.x;
    const int wv   = tid >> 6;               // 0..6
    const int lane = tid & 63;
    const int fm   = lane & 31;
    const int fq   = lane >> 5;

    if (wv < 4) {
        // ========================= MFMA waves ==============================
        const int mh = wv >> 1;              // t-half of chunk tile
        const int nh = wv & 1;               // n-half of panel

        // ---- B prologue: W[n0+nh*32+fm][:] -> hi/lo f16 register frags ----
        f16x8 bh[16], bl[16];
        {
            const float* wp = W + (size_t)(n0 + nh * 32 + fm) * KK_ + fq * 8;
#pragma unroll
            for (int ks = 0; ks < 16; ++ks) {
                float4 v0 = *(const float4*)(wp + ks * 16);
                float4 v1 = *(const float4*)(wp + ks * 16 + 4);
                float v[8] = {v0.x, v0.y, v0.z, v0.w, v1.x, v1.y, v1.z, v1.w};
                f16x8 h, l;
#pragma unroll
                for (int j = 0; j < 8; ++j) {
                    const f16 hj = (f16)v[j];
                    h[j] = hj;
                    l[j] = (f16)((v[j] - (float)hj) * 2048.0f);
                }
                bh[ks] = h; bl[ks] = l;
            }
        }

        f32x16 accH, accLa, accLb;
#pragma unroll
        for (int e = 0; e < 16; ++e) { accH[e] = 0.0f; accLa[e] = 0.0f; accLb[e] = 0.0f; }

        const int row = mh * 32 + fm;
        const int r15 = row & 15;

        auto compute_half = [&](int hf) {
            __builtin_amdgcn_s_setprio(1);
#pragma unroll
            for (int ks = 0; ks < 8; ++ks) {
                const int addr = row * KH_ + (((ks * 2 + fq) ^ r15) * 8);
                const f16x8 ah = *(const f16x8*)&Ah[hf][addr];
                const f16x8 al = *(const f16x8*)&Al[hf][addr];
                const int ksg = hf * 8 + ks;
                accH  = __builtin_amdgcn_mfma_f32_32x32x16_f16(ah, bh[ksg], accH,  0, 0, 0);
                accLa = __builtin_amdgcn_mfma_f32_32x32x16_f16(ah, bl[ksg], accLa, 0, 0, 0);
                accLb = __builtin_amdgcn_mfma_f32_32x32x16_f16(al, bh[ksg], accLb, 0, 0, 0);
            }
            __builtin_amdgcn_s_setprio(0);
        };

        barrier_lds();                            // prologue barrier
        for (int c = 0; c < NC_; ++c) {
            // phase 2c: MFMA on (c, kh0) from buf0; stagers fill buf1
            compute_half(0);
            barrier_lds();
            // phase 2c+1: MFMA on (c, kh1) from buf1 + epilogue -> wxbuf[c&1]
            compute_half(1);
            {
                float* wb = &wxbuf[c & 1][0];
                const int colw = nh * 32 + fm;
#pragma unroll
                for (int r = 0; r < 16; ++r) {
                    const int roww = mh * 32 + (r & 3) + 8 * (r >> 2) + 4 * fq;
                    wb[roww * 64 + colw] = accH[r] + (accLa[r] + accLb[r]) * (1.0f / 2048.0f);
                    accH[r] = 0.0f; accLa[r] = 0.0f; accLb[r] = 0.0f;
                }
            }
            barrier_lds();
        }
    } else if (wv < 6) {
        // ========================= stager waves ============================
        // wave u covers rows u*32 .. u*32+31 of the 64-row chunk tile.
        // instr j covers rows u*32 + j*2 + {0,1}; 32 lanes x 16 B = one
        // contiguous 512 B k-half row -> coalesced.
        const int u      = wv - 4;
        const int srow_j = u * 32 + (lane >> 5);    // + j*2
        const int f4i    = lane & 31;
        const int g      = f4i >> 1;                // 8-f16 group 0..15
        const int sub    = f4i & 1;

        float4 pend[16];
        auto issue_loads = [&](int c, int kh) {
            const float* base = X + ((size_t)b * TT_ + c * TC_) * KK_ + kh * KH_ + f4i * 4;
#pragma unroll
            for (int j = 0; j < 16; ++j)
                pend[j] = *(const float4*)(base + (size_t)(srow_j + j * 2) * KK_);
        };
        auto cvt_write = [&](int bufi) {
#pragma unroll
            for (int j = 0; j < 16; ++j) {
                const int rowa = srow_j + j * 2;
                const float v[4] = {pend[j].x, pend[j].y, pend[j].z, pend[j].w};
                f16x4 h, l;
#pragma unroll
                for (int e = 0; e < 4; ++e) {
                    const f16 he = (f16)v[e];
                    h[e] = he;
                    l[e] = (f16)((v[e] - (float)he) * 2048.0f);
                }
                const int addr = rowa * KH_ + ((g ^ (rowa & 15)) * 8) + sub * 4;
                *(f16x4*)&Ah[bufi][addr] = h;
                *(f16x4*)&Al[bufi][addr] = l;
            }
        };

        // prologue: stage (0,0) -> buf0; leave (0,1) loads in flight
        issue_loads(0, 0);
        cvt_write(0);                 // compiler inserts vmcnt wait on pend
        issue_loads(0, 1);
        barrier_lds();                // prologue barrier

        for (int c = 0; c < NC_; ++c) {
            // phase 2c: buf1 <- (c,1); issue (c+1,0)
            cvt_write(1);
            if (c + 1 < NC_) issue_loads(c + 1, 0);
            barrier_lds();
            // phase 2c+1: buf0 <- (c+1,0); issue (c+1,1)
            if (c + 1 < NC_) { cvt_write(0); issue_loads(c + 1, 1); }
            barrier_lds();
        }
    } else {
        // ========================= scan wave (wv==6) =======================
        const int h = n0 + lane;
        const int chain = b * HH_ + h;
        float a = alpha[h];
        a = fminf(fmaxf(a, ALPHA_MIN), ALPHA_MAX);
        const float bbv = 1.0f - a;
        float u = u0[chain];
        float s = s0[chain];
        float* op = out + (size_t)b * TT_ * HH_ + h;

        auto consume = [&](int c, int hf) {
            const float* wb = &wxbuf[c & 1][0];
            const int tb = c * TC_ + hf * 32;
#pragma unroll
            for (int t0 = 0; t0 < 32; t0 += 8) {
                float w[8];
#pragma unroll
                for (int j = 0; j < 8; ++j) w[j] = wb[(hf * 32 + t0 + j) * 64 + lane];
#pragma unroll
                for (int j = 0; j < 8; ++j) {
                    u = fmaf(a, u - s, bbv * w[j]);
                    s = (u > 1.0f) ? 1.0f : 0.0f;
                    __builtin_nontemporal_store(s, &op[(size_t)(tb + t0 + j) * HH_]);
                }
            }
        };

        barrier_lds();                // prologue barrier
        for (int c = 0; c < NC_; ++c) {
            if (c) consume(c - 1, 0); // overlaps phase 2c
            barrier_lds();
            if (c) consume(c - 1, 1); // overlaps phase 2c+1
            barrier_lds();
        }
        consume(NC_ - 1, 0);
        consume(NC_ - 1, 1);
    }
}

// =================== generic fallback (non-reference shapes) ================
__global__ void gemm_naive(const float* __restrict__ X, const float* __restrict__ W,
                           float* __restrict__ C, int M, int N, int K)
{
    const int idx = blockIdx.x * 256 + threadIdx.x;
    if (idx >= M * N) return;
    const int m = idx / N, n = idx % N;
    float acc = 0.0f;
    for (int k = 0; k < K; ++k) acc = fmaf(X[(size_t)m * K + k], W[(size_t)n * K + k], acc);
    C[idx] = acc;
}

__global__ __launch_bounds__(64) void lif_scan_inplace(
    float* __restrict__ buf, const float* __restrict__ alpha,
    const float* __restrict__ u0, const float* __restrict__ s0, int T, int H)
{
    const int chain = blockIdx.x * 64 + threadIdx.x;
    const int h = chain % H;
    const int b = chain / H;
    float a = alpha[h];
    a = fminf(fmaxf(a, ALPHA_MIN), ALPHA_MAX);
    const float bb = 1.0f - a;
    float u = u0[chain], s = s0[chain];
    float* base = buf + (size_t)b * T * H + h;
    for (int t = 0; t < T; ++t) {
        u = fmaf(a, u - s, bb * base[(size_t)t * H]);
        s = (u > 1.0f) ? 1.0f : 0.0f;
        base[(size_t)t * H] = s;
    }
}

// ---------------- launch ----------------------------------------------------
extern "C" void kernel_launch(void* const* d_in, const int* in_sizes, int n_in,
                              void* d_out, int out_size, void* d_ws, size_t ws_size,
                              hipStream_t stream) {
    const float* x     = (const float*)d_in[0];
    const float* W     = (const float*)d_in[1];
    const float* alpha = (const float*)d_in[2];
    const float* u0    = (const float*)d_in[3];
    const float* s0    = (const float*)d_in[4];
    float* out = (float*)d_out;

    const int H = in_sizes[2];
    const int I = in_sizes[1] / H;
    const int B = in_sizes[3] / H;
    const int T = in_sizes[0] / (B * I);

    if (B == BB_ && T == TT_ && I == KK_ && H == HH_) {
        lif_fused5<<<256, 448, 0, stream>>>(x, W, alpha, u0, s0, out);
    } else {
        const int M = B * T;
        gemm_naive<<<(M * H + 255) / 256, 256, 0, stream>>>(x, W, out, M, H, I);
        lif_scan_inplace<<<(B * H + 63) / 64, 64, 0, stream>>>(out, alpha, u0, s0, T, H);
    }
}

// Round 2
// 275.974 us; speedup vs baseline: 1.0152x; 1.0142x over previous
//
#include <hip/hip_runtime.h>

#define ALPHA_MIN 0.8187307530779818f  // exp(-1/5)
#define ALPHA_MAX 0.9607894391523232f  // exp(-1/25)

typedef _Float16 f16;
typedef _Float16 f16x4 __attribute__((ext_vector_type(4)));
typedef _Float16 f16x8 __attribute__((ext_vector_type(8)));
typedef float f32x16 __attribute__((ext_vector_type(16)));

// Fixed problem shape
#define BB_ 32
#define TT_ 2048
#define KK_ 256
#define HH_ 512
#define TC_ 64               // timesteps per chunk
#define NC_ 32               // chunks
#define KH_ 128              // k-half (two halves of K=256)

// Barrier WITHOUT vmcnt drain: waits LDS ops only, leaves global loads in
// flight across the barrier (AITER-style). imm 0xC07F = vmcnt(63) expcnt(7)
// lgkmcnt(0) on gfx9 encoding.
__device__ __forceinline__ void barrier_lds() {
    __builtin_amdgcn_s_waitcnt(0xC07F);
    __builtin_amdgcn_s_barrier();
}

// ============================ fused kernel v6 ===============================
// grid 256 = (nt<<5)|b -> XCD = b%8: the 8 n-panel blocks of batch b share
// X[b] (2 MB) in one XCD L2.
// block 576 = 9 waves, ROLE-SPECIALIZED producer/consumer:
//   waves 0-3 : MFMA only (one 32x32 mfma tile each).
//   waves 4-7 : stagers — each owns 16 rows of the 64-row chunk tile;
//               global float4 loads with DEPTH-2 register prefetch (pA/pB),
//               fp32->f16 hi/lo split, swizzled LDS write.
//   wave  8   : LIF scan, consumes chunk c-1 from wxbuf.
// Half-step s (= 2c+kh) timeline, steady state:
//   loads for half s issued at phase s-2  -> TWO full phases of latency cover
//   cvt of half s+1 into buf[(s+1)&1] during phase s (MFMA eats buf[s&1])
// 2 barriers/chunk, 65 total.
// fp16-split: C = Ah*Bh + 2^-11*(Ah*Bl + Al*Bh); B-panel in registers
// (bh/bl = 64 VGPRs; f16x8 packs to 2 VGPRs — no spill, VGPR~112).
__global__ __launch_bounds__(576, 1) void lif_fused6(
    const float* __restrict__ X,      // (B,T,K)
    const float* __restrict__ W,      // (H,K)
    const float* __restrict__ alpha,  // (H)
    const float* __restrict__ u0,     // (B,H)
    const float* __restrict__ s0,     // (B,H)
    float* __restrict__ out)          // (B,T,H)
{
    __shared__ f16 Ah[2][TC_ * KH_];         // 2 x 16 KB (swizzled 8-f16 groups)
    __shared__ f16 Al[2][TC_ * KH_];         // 2 x 16 KB
    __shared__ float wxbuf[2][TC_ * 64];     // 32 KB
    // total LDS = 96 KB -> 1 block/CU

    const int b  = blockIdx.x & 31;
    const int nt = blockIdx.x >> 5;
    const int n0 = nt * 64;

    const int tid  = threadIdx.x;
    const int wv   = tid >> 6;               // 0..8
    const int lane = tid & 63;
    const int fm   = lane & 31;
    const int fq   = lane >> 5;

    if (wv < 4) {
        // ========================= MFMA waves ==============================
        const int mh = wv >> 1;              // t-half of chunk tile
        const int nh = wv & 1;               // n-half of panel

        // ---- B prologue: W[n0+nh*32+fm][:] -> hi/lo f16 register frags ----
        f16x8 bh[16], bl[16];
        {
            const float* wp = W + (size_t)(n0 + nh * 32 + fm) * KK_ + fq * 8;
#pragma unroll
            for (int ks = 0; ks < 16; ++ks) {
                float4 v0 = *(const float4*)(wp + ks * 16);
                float4 v1 = *(const float4*)(wp + ks * 16 + 4);
                float v[8] = {v0.x, v0.y, v0.z, v0.w, v1.x, v1.y, v1.z, v1.w};
                f16x8 h, l;
#pragma unroll
                for (int j = 0; j < 8; ++j) {
                    const f16 hj = (f16)v[j];
                    h[j] = hj;
                    l[j] = (f16)((v[j] - (float)hj) * 2048.0f);
                }
                bh[ks] = h; bl[ks] = l;
            }
        }

        f32x16 accH, accLa, accLb;
#pragma unroll
        for (int e = 0; e < 16; ++e) { accH[e] = 0.0f; accLa[e] = 0.0f; accLb[e] = 0.0f; }

        const int row = mh * 32 + fm;
        const int r15 = row & 15;

        auto compute_half = [&](int hf) {
            __builtin_amdgcn_s_setprio(1);
#pragma unroll
            for (int ks = 0; ks < 8; ++ks) {
                const int addr = row * KH_ + (((ks * 2 + fq) ^ r15) * 8);
                const f16x8 ah = *(const f16x8*)&Ah[hf][addr];
                const f16x8 al = *(const f16x8*)&Al[hf][addr];
                const int ksg = hf * 8 + ks;
                accH  = __builtin_amdgcn_mfma_f32_32x32x16_f16(ah, bh[ksg], accH,  0, 0, 0);
                accLa = __builtin_amdgcn_mfma_f32_32x32x16_f16(ah, bl[ksg], accLa, 0, 0, 0);
                accLb = __builtin_amdgcn_mfma_f32_32x32x16_f16(al, bh[ksg], accLb, 0, 0, 0);
            }
            __builtin_amdgcn_s_setprio(0);
        };

        barrier_lds();                            // prologue barrier
        for (int c = 0; c < NC_; ++c) {
            // phase 2c: MFMA on (c, kh0) from buf0; stagers fill buf1
            compute_half(0);
            barrier_lds();
            // phase 2c+1: MFMA on (c, kh1) from buf1 + epilogue -> wxbuf[c&1]
            compute_half(1);
            {
                float* wb = &wxbuf[c & 1][0];
                const int colw = nh * 32 + fm;
#pragma unroll
                for (int r = 0; r < 16; ++r) {
                    const int roww = mh * 32 + (r & 3) + 8 * (r >> 2) + 4 * fq;
                    wb[roww * 64 + colw] = accH[r] + (accLa[r] + accLb[r]) * (1.0f / 2048.0f);
                    accH[r] = 0.0f; accLa[r] = 0.0f; accLb[r] = 0.0f;
                }
            }
            barrier_lds();
        }
    } else if (wv < 8) {
        // ========================= stager waves ============================
        // wave u owns rows u*16 .. u*16+15 of the 64-row chunk tile.
        // instr j covers rows u*16 + j*2 + {0,1}; 32 lanes x 16 B = one
        // contiguous 512 B k-half row -> coalesced.
        // Depth-2 prefetch: pA holds even half-steps, pB odd half-steps;
        // static register indexing only (no runtime batch index -> no scratch).
        const int u      = wv - 4;
        const int srow_j = u * 16 + (lane >> 5);    // + j*2
        const int f4i    = lane & 31;
        const int g      = f4i >> 1;                // 8-f16 group 0..15
        const int sub    = f4i & 1;

        float4 pA[8], pB[8];

        auto issueA = [&](int hs) {                 // even half-step -> pA
            const int c = hs >> 1, kh = hs & 1;
            const float* base = X + ((size_t)b * TT_ + c * TC_) * KK_ + kh * KH_ + f4i * 4;
#pragma unroll
            for (int j = 0; j < 8; ++j)
                pA[j] = *(const float4*)(base + (size_t)(srow_j + j * 2) * KK_);
        };
        auto issueB = [&](int hs) {                 // odd half-step -> pB
            const int c = hs >> 1, kh = hs & 1;
            const float* base = X + ((size_t)b * TT_ + c * TC_) * KK_ + kh * KH_ + f4i * 4;
#pragma unroll
            for (int j = 0; j < 8; ++j)
                pB[j] = *(const float4*)(base + (size_t)(srow_j + j * 2) * KK_);
        };
        auto cvtA = [&](int bufi) {                 // pA -> buf[bufi]
#pragma unroll
            for (int j = 0; j < 8; ++j) {
                const int rowa = srow_j + j * 2;
                const float v[4] = {pA[j].x, pA[j].y, pA[j].z, pA[j].w};
                f16x4 h, l;
#pragma unroll
                for (int e = 0; e < 4; ++e) {
                    const f16 he = (f16)v[e];
                    h[e] = he;
                    l[e] = (f16)((v[e] - (float)he) * 2048.0f);
                }
                const int addr = rowa * KH_ + ((g ^ (rowa & 15)) * 8) + sub * 4;
                *(f16x4*)&Ah[bufi][addr] = h;
                *(f16x4*)&Al[bufi][addr] = l;
            }
        };
        auto cvtB = [&](int bufi) {                 // pB -> buf[bufi]
#pragma unroll
            for (int j = 0; j < 8; ++j) {
                const int rowa = srow_j + j * 2;
                const float v[4] = {pB[j].x, pB[j].y, pB[j].z, pB[j].w};
                f16x4 h, l;
#pragma unroll
                for (int e = 0; e < 4; ++e) {
                    const f16 he = (f16)v[e];
                    h[e] = he;
                    l[e] = (f16)((v[e] - (float)he) * 2048.0f);
                }
                const int addr = rowa * KH_ + ((g ^ (rowa & 15)) * 8) + sub * 4;
                *(f16x4*)&Ah[bufi][addr] = h;
                *(f16x4*)&Al[bufi][addr] = l;
            }
        };

        // prologue: h0 -> buf0; leave h1, h2 in flight
        issueA(0);                    // h0 -> pA
        issueB(1);                    // h1 -> pB
        cvtA(0);                      // h0 -> buf0 (waits pA only)
        issueA(2);                    // h2 -> pA
        barrier_lds();                // prologue barrier

        for (int c = 0; c < NC_; ++c) {
            // phase 2c: buf1 <- h(2c+1) from pB; issue h(2c+3) -> pB
            cvtB(1);
            if (c < NC_ - 1) issueB(2 * c + 3);
            barrier_lds();
            // phase 2c+1: buf0 <- h(2c+2) from pA; issue h(2c+4) -> pA
            if (c < NC_ - 1) cvtA(0);
            if (c < NC_ - 2) issueA(2 * c + 4);
            barrier_lds();
        }
    } else {
        // ========================= scan wave (wv==8) =======================
        const int h = n0 + lane;
        const int chain = b * HH_ + h;
        float a = alpha[h];
        a = fminf(fmaxf(a, ALPHA_MIN), ALPHA_MAX);
        const float bbv = 1.0f - a;
        float u = u0[chain];
        float s = s0[chain];
        float* op = out + (size_t)b * TT_ * HH_ + h;

        auto consume = [&](int c, int hf) {
            const float* wb = &wxbuf[c & 1][0];
            const int tb = c * TC_ + hf * 32;
#pragma unroll
            for (int t0 = 0; t0 < 32; t0 += 8) {
                float w[8];
#pragma unroll
                for (int j = 0; j < 8; ++j) w[j] = wb[(hf * 32 + t0 + j) * 64 + lane];
#pragma unroll
                for (int j = 0; j < 8; ++j) {
                    u = fmaf(a, u - s, bbv * w[j]);
                    s = (u > 1.0f) ? 1.0f : 0.0f;
                    __builtin_nontemporal_store(s, &op[(size_t)(tb + t0 + j) * HH_]);
                }
            }
        };

        barrier_lds();                // prologue barrier
        for (int c = 0; c < NC_; ++c) {
            if (c) consume(c - 1, 0); // overlaps phase 2c
            barrier_lds();
            if (c) consume(c - 1, 1); // overlaps phase 2c+1
            barrier_lds();
        }
        consume(NC_ - 1, 0);
        consume(NC_ - 1, 1);
    }
}

// =================== generic fallback (non-reference shapes) ================
__global__ void gemm_naive(const float* __restrict__ X, const float* __restrict__ W,
                           float* __restrict__ C, int M, int N, int K)
{
    const int idx = blockIdx.x * 256 + threadIdx.x;
    if (idx >= M * N) return;
    const int m = idx / N, n = idx % N;
    float acc = 0.0f;
    for (int k = 0; k < K; ++k) acc = fmaf(X[(size_t)m * K + k], W[(size_t)n * K + k], acc);
    C[idx] = acc;
}

__global__ __launch_bounds__(64) void lif_scan_inplace(
    float* __restrict__ buf, const float* __restrict__ alpha,
    const float* __restrict__ u0, const float* __restrict__ s0, int T, int H)
{
    const int chain = blockIdx.x * 64 + threadIdx.x;
    const int h = chain % H;
    const int b = chain / H;
    float a = alpha[h];
    a = fminf(fmaxf(a, ALPHA_MIN), ALPHA_MAX);
    const float bb = 1.0f - a;
    float u = u0[chain], s = s0[chain];
    float* base = buf + (size_t)b * T * H + h;
    for (int t = 0; t < T; ++t) {
        u = fmaf(a, u - s, bb * base[(size_t)t * H]);
        s = (u > 1.0f) ? 1.0f : 0.0f;
        base[(size_t)t * H] = s;
    }
}

// ---------------- launch ----------------------------------------------------
extern "C" void kernel_launch(void* const* d_in, const int* in_sizes, int n_in,
                              void* d_out, int out_size, void* d_ws, size_t ws_size,
                              hipStream_t stream) {
    const float* x     = (const float*)d_in[0];
    const float* W     = (const float*)d_in[1];
    const float* alpha = (const float*)d_in[2];
    const float* u0    = (const float*)d_in[3];
    const float* s0    = (const float*)d_in[4];
    float* out = (float*)d_out;

    const int H = in_sizes[2];
    const int I = in_sizes[1] / H;
    const int B = in_sizes[3] / H;
    const int T = in_sizes[0] / (B * I);

    if (B == BB_ && T == TT_ && I == KK_ && H == HH_) {
        lif_fused6<<<256, 576, 0, stream>>>(x, W, alpha, u0, s0, out);
    } else {
        const int M = B * T;
        gemm_naive<<<(M * H + 255) / 256, 256, 0, stream>>>(x, W, out, M, H, I);
        lif_scan_inplace<<<(B * H + 63) / 64, 64, 0, stream>>>(out, alpha, u0, s0, T, H);
    }
}

// Round 3
// 275.605 us; speedup vs baseline: 1.0165x; 1.0013x over previous
//
#include <hip/hip_runtime.h>

#define ALPHA_MIN 0.8187307530779818f  // exp(-1/5)
#define ALPHA_MAX 0.9607894391523232f  // exp(-1/25)

typedef _Float16 f16;
typedef _Float16 f16x4 __attribute__((ext_vector_type(4)));
typedef _Float16 f16x8 __attribute__((ext_vector_type(8)));
typedef float f32x16 __attribute__((ext_vector_type(16)));

// Fixed problem shape
#define BB_ 32
#define TT_ 2048
#define KK_ 256
#define HH_ 512
#define TC_ 64               // timesteps per chunk
#define NC_ 32               // chunks
#define KH_ 128              // k-half (two halves of K=256)

// Barrier WITHOUT vmcnt drain: waits LDS ops only, leaves global loads in
// flight across the barrier (AITER-style). imm 0xC07F = vmcnt(63) expcnt(7)
// lgkmcnt(0) on gfx9 encoding.
__device__ __forceinline__ void barrier_lds() {
    __builtin_amdgcn_s_waitcnt(0xC07F);
    __builtin_amdgcn_s_barrier();
}

// ============================ fused kernel v7 ===============================
// v7 = v6 with ONE change: output stores are normal write-back stores, NOT
// __builtin_nontemporal_store. Theory: NT streams bypass L2 write-combining,
// so the MC saw 256 B slices at 2 KB stride -> ~1/8 page utilization -> the
// ~1.0 TB/s write ceiling that pinned v4/v5/v6 at dur ~= WRITE/1TBs. With
// write-back allocation, the 8 same-b nt-panel blocks (co-located on one XCD
// by the grid swizzle, running in lockstep) dirty all eight 256 B slices of
// each 2 KB output row in the same L2 before eviction -> full-row writebacks.
//
// grid 256 = (nt<<5)|b -> XCD = b%8.
// block 576 = 9 waves, ROLE-SPECIALIZED producer/consumer:
//   waves 0-3 : MFMA only (one 32x32 mfma tile each).
//   waves 4-7 : stagers — each owns 16 rows of the 64-row chunk tile;
//               global float4 loads with DEPTH-2 register prefetch (pA/pB),
//               fp32->f16 hi/lo split, swizzled LDS write.
//   wave  8   : LIF scan, consumes chunk c-1 from wxbuf.
// fp16-split: C = Ah*Bh + 2^-11*(Ah*Bl + Al*Bh); B-panel in registers.
__global__ __launch_bounds__(576, 1) void lif_fused7(
    const float* __restrict__ X,      // (B,T,K)
    const float* __restrict__ W,      // (H,K)
    const float* __restrict__ alpha,  // (H)
    const float* __restrict__ u0,     // (B,H)
    const float* __restrict__ s0,     // (B,H)
    float* __restrict__ out)          // (B,T,H)
{
    __shared__ f16 Ah[2][TC_ * KH_];         // 2 x 16 KB (swizzled 8-f16 groups)
    __shared__ f16 Al[2][TC_ * KH_];         // 2 x 16 KB
    __shared__ float wxbuf[2][TC_ * 64];     // 32 KB
    // total LDS = 96 KB -> 1 block/CU

    const int b  = blockIdx.x & 31;
    const int nt = blockIdx.x >> 5;
    const int n0 = nt * 64;

    const int tid  = threadIdx.x;
    const int wv   = tid >> 6;               // 0..8
    const int lane = tid & 63;
    const int fm   = lane & 31;
    const int fq   = lane >> 5;

    if (wv < 4) {
        // ========================= MFMA waves ==============================
        const int mh = wv >> 1;              // t-half of chunk tile
        const int nh = wv & 1;               // n-half of panel

        // ---- B prologue: W[n0+nh*32+fm][:] -> hi/lo f16 register frags ----
        f16x8 bh[16], bl[16];
        {
            const float* wp = W + (size_t)(n0 + nh * 32 + fm) * KK_ + fq * 8;
#pragma unroll
            for (int ks = 0; ks < 16; ++ks) {
                float4 v0 = *(const float4*)(wp + ks * 16);
                float4 v1 = *(const float4*)(wp + ks * 16 + 4);
                float v[8] = {v0.x, v0.y, v0.z, v0.w, v1.x, v1.y, v1.z, v1.w};
                f16x8 h, l;
#pragma unroll
                for (int j = 0; j < 8; ++j) {
                    const f16 hj = (f16)v[j];
                    h[j] = hj;
                    l[j] = (f16)((v[j] - (float)hj) * 2048.0f);
                }
                bh[ks] = h; bl[ks] = l;
            }
        }

        f32x16 accH, accLa, accLb;
#pragma unroll
        for (int e = 0; e < 16; ++e) { accH[e] = 0.0f; accLa[e] = 0.0f; accLb[e] = 0.0f; }

        const int row = mh * 32 + fm;
        const int r15 = row & 15;

        auto compute_half = [&](int hf) {
            __builtin_amdgcn_s_setprio(1);
#pragma unroll
            for (int ks = 0; ks < 8; ++ks) {
                const int addr = row * KH_ + (((ks * 2 + fq) ^ r15) * 8);
                const f16x8 ah = *(const f16x8*)&Ah[hf][addr];
                const f16x8 al = *(const f16x8*)&Al[hf][addr];
                const int ksg = hf * 8 + ks;
                accH  = __builtin_amdgcn_mfma_f32_32x32x16_f16(ah, bh[ksg], accH,  0, 0, 0);
                accLa = __builtin_amdgcn_mfma_f32_32x32x16_f16(ah, bl[ksg], accLa, 0, 0, 0);
                accLb = __builtin_amdgcn_mfma_f32_32x32x16_f16(al, bh[ksg], accLb, 0, 0, 0);
            }
            __builtin_amdgcn_s_setprio(0);
        };

        barrier_lds();                            // prologue barrier
        for (int c = 0; c < NC_; ++c) {
            // phase 2c: MFMA on (c, kh0) from buf0; stagers fill buf1
            compute_half(0);
            barrier_lds();
            // phase 2c+1: MFMA on (c, kh1) from buf1 + epilogue -> wxbuf[c&1]
            compute_half(1);
            {
                float* wb = &wxbuf[c & 1][0];
                const int colw = nh * 32 + fm;
#pragma unroll
                for (int r = 0; r < 16; ++r) {
                    const int roww = mh * 32 + (r & 3) + 8 * (r >> 2) + 4 * fq;
                    wb[roww * 64 + colw] = accH[r] + (accLa[r] + accLb[r]) * (1.0f / 2048.0f);
                    accH[r] = 0.0f; accLa[r] = 0.0f; accLb[r] = 0.0f;
                }
            }
            barrier_lds();
        }
    } else if (wv < 8) {
        // ========================= stager waves ============================
        // wave u owns rows u*16 .. u*16+15 of the 64-row chunk tile.
        // instr j covers rows u*16 + j*2 + {0,1}; 32 lanes x 16 B = one
        // contiguous 512 B k-half row -> coalesced.
        // Depth-2 prefetch: pA holds even half-steps, pB odd half-steps;
        // static register indexing only (no runtime batch index -> no scratch).
        const int u      = wv - 4;
        const int srow_j = u * 16 + (lane >> 5);    // + j*2
        const int f4i    = lane & 31;
        const int g      = f4i >> 1;                // 8-f16 group 0..15
        const int sub    = f4i & 1;

        float4 pA[8], pB[8];

        auto issueA = [&](int hs) {                 // even half-step -> pA
            const int c = hs >> 1, kh = hs & 1;
            const float* base = X + ((size_t)b * TT_ + c * TC_) * KK_ + kh * KH_ + f4i * 4;
#pragma unroll
            for (int j = 0; j < 8; ++j)
                pA[j] = *(const float4*)(base + (size_t)(srow_j + j * 2) * KK_);
        };
        auto issueB = [&](int hs) {                 // odd half-step -> pB
            const int c = hs >> 1, kh = hs & 1;
            const float* base = X + ((size_t)b * TT_ + c * TC_) * KK_ + kh * KH_ + f4i * 4;
#pragma unroll
            for (int j = 0; j < 8; ++j)
                pB[j] = *(const float4*)(base + (size_t)(srow_j + j * 2) * KK_);
        };
        auto cvtA = [&](int bufi) {                 // pA -> buf[bufi]
#pragma unroll
            for (int j = 0; j < 8; ++j) {
                const int rowa = srow_j + j * 2;
                const float v[4] = {pA[j].x, pA[j].y, pA[j].z, pA[j].w};
                f16x4 h, l;
#pragma unroll
                for (int e = 0; e < 4; ++e) {
                    const f16 he = (f16)v[e];
                    h[e] = he;
                    l[e] = (f16)((v[e] - (float)he) * 2048.0f);
                }
                const int addr = rowa * KH_ + ((g ^ (rowa & 15)) * 8) + sub * 4;
                *(f16x4*)&Ah[bufi][addr] = h;
                *(f16x4*)&Al[bufi][addr] = l;
            }
        };
        auto cvtB = [&](int bufi) {                 // pB -> buf[bufi]
#pragma unroll
            for (int j = 0; j < 8; ++j) {
                const int rowa = srow_j + j * 2;
                const float v[4] = {pB[j].x, pB[j].y, pB[j].z, pB[j].w};
                f16x4 h, l;
#pragma unroll
                for (int e = 0; e < 4; ++e) {
                    const f16 he = (f16)v[e];
                    h[e] = he;
                    l[e] = (f16)((v[e] - (float)he) * 2048.0f);
                }
                const int addr = rowa * KH_ + ((g ^ (rowa & 15)) * 8) + sub * 4;
                *(f16x4*)&Ah[bufi][addr] = h;
                *(f16x4*)&Al[bufi][addr] = l;
            }
        };

        // prologue: h0 -> buf0; leave h1, h2 in flight
        issueA(0);                    // h0 -> pA
        issueB(1);                    // h1 -> pB
        cvtA(0);                      // h0 -> buf0 (waits pA only)
        issueA(2);                    // h2 -> pA
        barrier_lds();                // prologue barrier

        for (int c = 0; c < NC_; ++c) {
            // phase 2c: buf1 <- h(2c+1) from pB; issue h(2c+3) -> pB
            cvtB(1);
            if (c < NC_ - 1) issueB(2 * c + 3);
            barrier_lds();
            // phase 2c+1: buf0 <- h(2c+2) from pA; issue h(2c+4) -> pA
            if (c < NC_ - 1) cvtA(0);
            if (c < NC_ - 2) issueA(2 * c + 4);
            barrier_lds();
        }
    } else {
        // ========================= scan wave (wv==8) =======================
        const int h = n0 + lane;
        const int chain = b * HH_ + h;
        float a = alpha[h];
        a = fminf(fmaxf(a, ALPHA_MIN), ALPHA_MAX);
        const float bbv = 1.0f - a;
        float u = u0[chain];
        float s = s0[chain];
        float* op = out + (size_t)b * TT_ * HH_ + h;

        auto consume = [&](int c, int hf) {
            const float* wb = &wxbuf[c & 1][0];
            const int tb = c * TC_ + hf * 32;
#pragma unroll
            for (int t0 = 0; t0 < 32; t0 += 8) {
                float w[8];
#pragma unroll
                for (int j = 0; j < 8; ++j) w[j] = wb[(hf * 32 + t0 + j) * 64 + lane];
#pragma unroll
                for (int j = 0; j < 8; ++j) {
                    u = fmaf(a, u - s, bbv * w[j]);
                    s = (u > 1.0f) ? 1.0f : 0.0f;
                    // v7: PLAIN write-back store (was nontemporal). Allocates
                    // in the shared XCD L2 so the 8 same-b panel blocks merge
                    // their 256 B slices into full 2 KB rows before writeback.
                    op[(size_t)(tb + t0 + j) * HH_] = s;
                }
            }
        };

        barrier_lds();                // prologue barrier
        for (int c = 0; c < NC_; ++c) {
            if (c) consume(c - 1, 0); // overlaps phase 2c
            barrier_lds();
            if (c) consume(c - 1, 1); // overlaps phase 2c+1
            barrier_lds();
        }
        consume(NC_ - 1, 0);
        consume(NC_ - 1, 1);
    }
}

// =================== generic fallback (non-reference shapes) ================
__global__ void gemm_naive(const float* __restrict__ X, const float* __restrict__ W,
                           float* __restrict__ C, int M, int N, int K)
{
    const int idx = blockIdx.x * 256 + threadIdx.x;
    if (idx >= M * N) return;
    const int m = idx / N, n = idx % N;
    float acc = 0.0f;
    for (int k = 0; k < K; ++k) acc = fmaf(X[(size_t)m * K + k], W[(size_t)n * K + k], acc);
    C[idx] = acc;
}

__global__ __launch_bounds__(64) void lif_scan_inplace(
    float* __restrict__ buf, const float* __restrict__ alpha,
    const float* __restrict__ u0, const float* __restrict__ s0, int T, int H)
{
    const int chain = blockIdx.x * 64 + threadIdx.x;
    const int h = chain % H;
    const int b = chain / H;
    float a = alpha[h];
    a = fminf(fmaxf(a, ALPHA_MIN), ALPHA_MAX);
    const float bb = 1.0f - a;
    float u = u0[chain], s = s0[chain];
    float* base = buf + (size_t)b * T * H + h;
    for (int t = 0; t < T; ++t) {
        u = fmaf(a, u - s, bb * base[(size_t)t * H]);
        s = (u > 1.0f) ? 1.0f : 0.0f;
        base[(size_t)t * H] = s;
    }
}

// ---------------- launch ----------------------------------------------------
extern "C" void kernel_launch(void* const* d_in, const int* in_sizes, int n_in,
                              void* d_out, int out_size, void* d_ws, size_t ws_size,
                              hipStream_t stream) {
    const float* x     = (const float*)d_in[0];
    const float* W     = (const float*)d_in[1];
    const float* alpha = (const float*)d_in[2];
    const float* u0    = (const float*)d_in[3];
    const float* s0    = (const float*)d_in[4];
    float* out = (float*)d_out;

    const int H = in_sizes[2];
    const int I = in_sizes[1] / H;
    const int B = in_sizes[3] / H;
    const int T = in_sizes[0] / (B * I);

    if (B == BB_ && T == TT_ && I == KK_ && H == HH_) {
        lif_fused7<<<256, 576, 0, stream>>>(x, W, alpha, u0, s0, out);
    } else {
        const int M = B * T;
        gemm_naive<<<(M * H + 255) / 256, 256, 0, stream>>>(x, W, out, M, H, I);
        lif_scan_inplace<<<(B * H + 63) / 64, 64, 0, stream>>>(out, alpha, u0, s0, T, H);
    }
}